// Round 2
// baseline (216.040 us; speedup 1.0000x reference)
//
#include <hip/hip_runtime.h>

#define S_LEN 1024
#define CIN 512
#define NH 8
#define DH 64
#define NJ 512
#define NB 8

typedef short bf16x8 __attribute__((ext_vector_type(8)));
typedef float f32x4 __attribute__((ext_vector_type(4)));
typedef unsigned short u16x4 __attribute__((ext_vector_type(4)));

__device__ inline unsigned short f2bf(float f){
  union { float f; unsigned u; } v; v.f = f;
  unsigned r = v.u + 0x7FFFu + ((v.u >> 16) & 1u);
  return (unsigned short)(r >> 16);
}

// swizzled frag load: LDS tile rows of 64 bf16 (128B), XOR swizzle ^((row&7)<<4)
__device__ inline bf16x8 ldfrag(const unsigned short* lds, int row, int kbyte){
  return *(const bf16x8*)((const char*)lds + row*128 + (kbyte ^ ((row & 7) << 4)));
}

// stage a 64x64 fp32 tile from global [k][m] (m-fastest) into LDS [m][k] bf16, swizzled.
// coalesced float4 reads along m, 4x4 in-register transpose, b64 LDS writes.
__device__ inline void stage_T(const float* __restrict__ src, int ld,
                               unsigned short* lds, int tid){
  int bm = tid & 15, bk = tid >> 4;
  const float* p = src + bk*4*ld + bm*4;
  float4 f0 = *(const float4*)(p);
  float4 f1 = *(const float4*)(p + ld);
  float4 f2 = *(const float4*)(p + 2*ld);
  float4 f3 = *(const float4*)(p + 3*ld);
  #pragma unroll
  for (int mm = 0; mm < 4; mm++){
    int row = bm*4 + mm;
    u16x4 w;
    w[0] = f2bf(((const float*)&f0)[mm]);
    w[1] = f2bf(((const float*)&f1)[mm]);
    w[2] = f2bf(((const float*)&f2)[mm]);
    w[3] = f2bf(((const float*)&f3)[mm]);
    *(u16x4*)((char*)lds + row*128 + ((bk*8) ^ ((row & 7) << 4))) = w;
  }
}

// D[64m x 64n] = A^T B, A global [K][M] m-fastest, B global [K][N] n-fastest, K=512.
// 4 waves: wave w owns rows w*16..w*16+15, all 64 cols. acc[nt] = 16x16 tile nt.
__device__ inline void gemm64(const float* Asrc, int lda, const float* Bsrc, int ldb,
                              unsigned short* As, unsigned short* Bs,
                              f32x4 acc[4], int tid){
  int lane = tid & 63, wid = tid >> 6;
  for (int k0 = 0; k0 < 512; k0 += 64){
    __syncthreads();
    stage_T(Asrc + k0*lda, lda, As, tid);
    stage_T(Bsrc + k0*ldb, ldb, Bs, tid);
    __syncthreads();
    #pragma unroll
    for (int kt = 0; kt < 2; kt++){
      bf16x8 af = ldfrag(As, wid*16 + (lane & 15), kt*64 + ((lane >> 4) << 4));
      #pragma unroll
      for (int nt = 0; nt < 4; nt++){
        bf16x8 bfr = ldfrag(Bs, nt*16 + (lane & 15), kt*64 + ((lane >> 4) << 4));
        acc[nt] = __builtin_amdgcn_mfma_f32_16x16x32_bf16(af, bfr, acc[nt], 0, 0, 0);
      }
    }
  }
}

// ---------------- kernel 1a: Q = xs@Wq+bq, K = xs@Wk+bk, stored [b][h][s][d] bf16
__global__ __launch_bounds__(256) void qk_proj(const float* __restrict__ x,
    const float* __restrict__ Wq, const float* __restrict__ bq,
    const float* __restrict__ Wk, const float* __restrict__ bk,
    unsigned short* __restrict__ q_ws, unsigned short* __restrict__ k_ws){
  __shared__ __align__(16) unsigned short As[4096], Bs[4096];
  int tid = threadIdx.x, lane = tid & 63, wid = tid >> 6;
  int m0 = blockIdx.x * 64;            // s
  int n0 = blockIdx.y * 64;            // j
  int z = blockIdx.z, b = z >> 1, isK = z & 1;
  const float* W    = isK ? Wk : Wq;
  const float* bias = isK ? bk : bq;
  unsigned short* dst = isK ? k_ws : q_ws;
  const float* Asrc = x + (size_t)b*CIN*S_LEN + m0;   // [c][s], ld S
  const float* Bsrc = W + n0;                          // [c][j], ld NJ
  f32x4 acc[4];
  #pragma unroll
  for (int i = 0; i < 4; i++) acc[i] = (f32x4){0.f,0.f,0.f,0.f};
  gemm64(Asrc, S_LEN, Bsrc, NJ, As, Bs, acc, tid);
  int h = n0 >> 6;
  size_t base = ((size_t)(b*NH + h)) * S_LEN;
  #pragma unroll
  for (int nt = 0; nt < 4; nt++){
    int j = n0 + nt*16 + (lane & 15);
    int d = nt*16 + (lane & 15);
    float bv_ = bias[j];
    #pragma unroll
    for (int r = 0; r < 4; r++){
      int s = m0 + wid*16 + (lane >> 4)*4 + r;
      dst[(base + s)*DH + d] = f2bf(acc[nt][r] + bv_);
    }
  }
}

// ---------------- kernel 1b: V^T = (xs@Wv+bv)^T, stored [b][h][d][s] bf16
__global__ __launch_bounds__(256) void vt_proj(const float* __restrict__ x,
    const float* __restrict__ Wv, const float* __restrict__ bv,
    unsigned short* __restrict__ vt_ws){
  __shared__ __align__(16) unsigned short As[4096], Bs[4096];
  int tid = threadIdx.x, lane = tid & 63, wid = tid >> 6;
  int m0 = blockIdx.x * 64;            // j
  int n0 = blockIdx.y * 64;            // s
  int b = blockIdx.z;
  const float* Asrc = Wv + m0;                         // [c][j], ld NJ
  const float* Bsrc = x + (size_t)b*CIN*S_LEN + n0;    // [c][s], ld S
  f32x4 acc[4];
  #pragma unroll
  for (int i = 0; i < 4; i++) acc[i] = (f32x4){0.f,0.f,0.f,0.f};
  gemm64(Asrc, NJ, Bsrc, S_LEN, As, Bs, acc, tid);
  int h = m0 >> 6;
  size_t base = ((size_t)(b*NH + h)) * DH;
  #pragma unroll
  for (int r = 0; r < 4; r++){
    int j  = m0 + wid*16 + (lane >> 4)*4 + r;
    int dv = j & 63;
    float bb = bv[j];
    #pragma unroll
    for (int nt = 0; nt < 4; nt++){
      int s = n0 + nt*16 + (lane & 15);
      vt_ws[(base + dv)*S_LEN + s] = f2bf(acc[nt][r] + bb);
    }
  }
}

// ---------------- kernel 2: flash attention per (b,h); out attn^T [b][j][s] fp32
__global__ __launch_bounds__(256) void attn_fwd(const unsigned short* __restrict__ qw,
    const unsigned short* __restrict__ kw, const unsigned short* __restrict__ vtw,
    float* __restrict__ atw){
  __shared__ __align__(16) unsigned short Ks[4096], Vs[4096], Ps[4096];
  int tid = threadIdx.x, lane = tid & 63, wid = tid >> 6;
  int qb = blockIdx.x;     // q block (64 rows)
  int bh = blockIdx.y;     // b*NH + h
  int q = qb*64 + wid*16 + (lane & 15);
  const unsigned short* qrow = qw + ((size_t)bh*S_LEN + q)*DH;
  bf16x8 qf0 = *(const bf16x8*)(qrow + ((lane >> 4) * 8));
  bf16x8 qf1 = *(const bf16x8*)(qrow + 32 + ((lane >> 4) * 8));
  unsigned short* myP = Ps + wid*1024;
  f32x4 oacc[4];
  #pragma unroll
  for (int i = 0; i < 4; i++) oacc[i] = (f32x4){0.f,0.f,0.f,0.f};
  float mrun = -1e30f, lrun = 0.f;

  for (int kv0 = 0; kv0 < S_LEN; kv0 += 64){
    __syncthreads();
    // stage K tile [64 kcol][64 d] and VT tile [64 d][64 kcol], swizzled b128
    for (int i = tid; i < 512; i += 256){
      int row = i >> 3, ch = i & 7;
      *(uint4*)((char*)Ks + row*128 + ((ch*16) ^ ((row & 7) << 4))) =
          *(const uint4*)(kw + ((size_t)bh*S_LEN + kv0 + row)*DH + ch*8);
      *(uint4*)((char*)Vs + row*128 + ((ch*16) ^ ((row & 7) << 4))) =
          *(const uint4*)(vtw + ((size_t)bh*DH + row)*S_LEN + kv0 + ch*8);
    }
    __syncthreads();

    // S^T tile: D'[kcol][q] via mfma(K, Q)
    f32x4 st[4];
    #pragma unroll
    for (int mt = 0; mt < 4; mt++){
      f32x4 a = (f32x4){0.f,0.f,0.f,0.f};
      a = __builtin_amdgcn_mfma_f32_16x16x32_bf16(
            ldfrag(Ks, mt*16 + (lane & 15), ((lane >> 4) << 4)), qf0, a, 0,0,0);
      a = __builtin_amdgcn_mfma_f32_16x16x32_bf16(
            ldfrag(Ks, mt*16 + (lane & 15), 64 + ((lane >> 4) << 4)), qf1, a, 0,0,0);
      st[mt] = a;
    }
    // scale + row max (row q = lane&15; partners differ in bits 4,5)
    float vmax = -1e30f;
    #pragma unroll
    for (int mt = 0; mt < 4; mt++){
      #pragma unroll
      for (int r = 0; r < 4; r++){
        st[mt][r] *= 0.125f;
        vmax = fmaxf(vmax, st[mt][r]);
      }
    }
    vmax = fmaxf(vmax, __shfl_xor(vmax, 16));
    vmax = fmaxf(vmax, __shfl_xor(vmax, 32));
    float mnew = fmaxf(mrun, vmax);
    float corr = __expf(mrun - mnew);
    float psum = 0.f;
    int qrw = lane & 15;
    #pragma unroll
    for (int mt = 0; mt < 4; mt++){
      float p0 = __expf(st[mt][0] - mnew);
      float p1 = __expf(st[mt][1] - mnew);
      float p2 = __expf(st[mt][2] - mnew);
      float p3 = __expf(st[mt][3] - mnew);
      psum += (p0 + p1) + (p2 + p3);
      u16x4 w; w[0]=f2bf(p0); w[1]=f2bf(p1); w[2]=f2bf(p2); w[3]=f2bf(p3);
      *(u16x4*)((char*)myP + qrw*128 + ((mt*32 + (lane >> 4)*8) ^ ((qrw & 7) << 4))) = w;
    }
    psum += __shfl_xor(psum, 16);
    psum += __shfl_xor(psum, 32);
    lrun = lrun * corr + psum;
    mrun = mnew;
    #pragma unroll
    for (int mt = 0; mt < 4; mt++) oacc[mt] *= corr;
    // O^T += V^T P^T : mfma(A=VT[dv][k], B=P[q][k])
    #pragma unroll
    for (int kt = 0; kt < 2; kt++){
      bf16x8 pf = *(const bf16x8*)((char*)myP + qrw*128 +
                    ((kt*64 + ((lane >> 4) << 4)) ^ ((qrw & 7) << 4)));
      #pragma unroll
      for (int mt = 0; mt < 4; mt++){
        oacc[mt] = __builtin_amdgcn_mfma_f32_16x16x32_bf16(
            ldfrag(Vs, mt*16 + (lane & 15), kt*64 + ((lane >> 4) << 4)), pf, oacc[mt], 0,0,0);
      }
    }
  }
  float inv = 1.f / lrun;
  size_t basev = (size_t)bh * DH;
  #pragma unroll
  for (int mt = 0; mt < 4; mt++){
    #pragma unroll
    for (int r = 0; r < 4; r++){
      int dv = mt*16 + (lane >> 4)*4 + r;
      atw[(basev + dv)*S_LEN + q] = oacc[mt][r] * inv;
    }
  }
}

// ---------------- kernel 3: out[b][c][s] = attn^T^T@Wo + bo + x  (D[c][s] orientation)
__global__ __launch_bounds__(256) void out_proj(const float* __restrict__ at,
    const float* __restrict__ Wo, const float* __restrict__ bo,
    const float* __restrict__ x, float* __restrict__ out){
  __shared__ __align__(16) unsigned short As[4096], Bs[4096];
  int tid = threadIdx.x, lane = tid & 63, wid = tid >> 6;
  int m0 = blockIdx.x * 64;            // c
  int n0 = blockIdx.y * 64;            // s
  int b = blockIdx.z;
  const float* Asrc = Wo + m0;                          // [j][c], ld CIN
  const float* Bsrc = at + (size_t)b*NJ*S_LEN + n0;     // [j][s], ld S
  f32x4 acc[4];
  #pragma unroll
  for (int i = 0; i < 4; i++) acc[i] = (f32x4){0.f,0.f,0.f,0.f};
  gemm64(Asrc, CIN, Bsrc, S_LEN, As, Bs, acc, tid);
  #pragma unroll
  for (int r = 0; r < 4; r++){
    int c = m0 + wid*16 + (lane >> 4)*4 + r;
    float bb = bo[c];
    #pragma unroll
    for (int nt = 0; nt < 4; nt++){
      int s = n0 + nt*16 + (lane & 15);
      size_t idx = ((size_t)b*CIN + c)*S_LEN + s;
      out[idx] = acc[nt][r] + bb + x[idx];
    }
  }
}

extern "C" void kernel_launch(void* const* d_in, const int* in_sizes, int n_in,
                              void* d_out, int out_size, void* d_ws, size_t ws_size,
                              hipStream_t stream){
  const float* x  = (const float*)d_in[0];
  const float* Wq = (const float*)d_in[1];
  const float* bq = (const float*)d_in[2];
  const float* Wk = (const float*)d_in[3];
  const float* bk = (const float*)d_in[4];
  const float* Wv = (const float*)d_in[5];
  const float* bv = (const float*)d_in[6];
  const float* Wo = (const float*)d_in[7];
  const float* bo = (const float*)d_in[8];
  float* out = (float*)d_out;

  const size_t qkv_elems = (size_t)NB*NH*S_LEN*DH;   // 4.19M bf16 each
  unsigned short* q_ws  = (unsigned short*)d_ws;
  unsigned short* k_ws  = q_ws + qkv_elems;
  unsigned short* vt_ws = k_ws + qkv_elems;
  float* at_ws = (float*)(vt_ws + qkv_elems);        // [b][j][s] fp32, 16.8MB

  qk_proj<<<dim3(16, 8, 16), 256, 0, stream>>>(x, Wq, bq, Wk, bk, q_ws, k_ws);
  vt_proj<<<dim3(8, 16, 8), 256, 0, stream>>>(x, Wv, bv, vt_ws);
  attn_fwd<<<dim3(16, 64), 256, 0, stream>>>(q_ws, k_ws, vt_ws, at_ws);
  out_proj<<<dim3(8, 16, 8), 256, 0, stream>>>(at_ws, Wo, bo, x, out);
}

// Round 6
// 168.569 us; speedup vs baseline: 1.2816x; 1.2816x over previous
//
#include <hip/hip_runtime.h>

#define S_LEN 1024
#define CIN 512
#define NH 8
#define DH 64
#define NB 8

typedef short bf16x8 __attribute__((ext_vector_type(8)));
typedef float f32x4 __attribute__((ext_vector_type(4)));
typedef unsigned short u16x4 __attribute__((ext_vector_type(4)));

__device__ inline unsigned short f2bf(float f){
  union { float f; unsigned u; } v; v.f = f;
  unsigned r = v.u + 0x7FFFu + ((v.u >> 16) & 1u);
  return (unsigned short)(r >> 16);
}

// async global->LDS, 16B per lane. LDS dest = base + lane*16 (wave-uniform base).
__device__ inline void gload16(const void* g, void* l){
  __builtin_amdgcn_global_load_lds(
      (const __attribute__((address_space(1))) unsigned*)g,
      (__attribute__((address_space(3))) unsigned*)l, 16, 0, 0);
}

// swizzled frag read from LDS tile with 128B rows: phys col = kbyte ^ ((row&7)<<4)
__device__ inline bf16x8 ldfrag(const unsigned short* lds, int row, int kbyte){
  return *(const bf16x8*)((const char*)lds + row*128 + (kbyte ^ ((row & 7) << 4)));
}

// ---------------- prep: transpose+convert fp32 -> bf16 (64x64 tiles) ----------------
// blocks 0..1023: x[b][c][s] -> xs[b][s][c]; 1024..1279: the 4 weight matrices.
__global__ __launch_bounds__(256) void prep(const float* __restrict__ x,
    const float* __restrict__ Wq, const float* __restrict__ Wk,
    const float* __restrict__ Wv, const float* __restrict__ Wo,
    unsigned short* __restrict__ xs, unsigned short* __restrict__ Wqkt,
    unsigned short* __restrict__ Wvt, unsigned short* __restrict__ Wot){
  __shared__ unsigned short T[64*72];
  int bid = blockIdx.x, t = threadIdx.x;
  const float* src; unsigned short* dst; int ldS, r0, c0;
  if (bid < 1024){
    int b = bid >> 7, tt = bid & 127;
    src = x + (size_t)b*CIN*S_LEN; ldS = S_LEN;
    dst = xs + (size_t)b*S_LEN*CIN;
    r0 = (tt >> 4) * 64;            // c
    c0 = (tt & 15) * 64;            // s
  } else {
    int w = bid - 1024, mat = w >> 6, tt = w & 63;
    r0 = (tt >> 3) * 64; c0 = (tt & 7) * 64; ldS = 512;
    if (mat == 0){ src = Wq; dst = Wqkt; }
    else if (mat == 1){ src = Wk; dst = Wqkt + 512*512; }
    else if (mat == 2){ src = Wv; dst = Wvt; }
    else            { src = Wo; dst = Wot; }
  }
  int rl = t >> 4, cb = (t & 15) * 4;
  #pragma unroll
  for (int rr = 0; rr < 4; rr++){
    float4 f = *(const float4*)(src + (size_t)(r0 + rl + rr*16)*ldS + c0 + cb);
    int rc = rl + rr*16;
    T[(cb+0)*72 + rc] = f2bf(f.x);
    T[(cb+1)*72 + rc] = f2bf(f.y);
    T[(cb+2)*72 + rc] = f2bf(f.z);
    T[(cb+3)*72 + rc] = f2bf(f.w);
  }
  __syncthreads();
  // write-back: each thread copies its FULL 16-element strip (2 x uint4).
  int cl = t >> 2, rb = (t & 3) * 16;
  uint4 v0 = *(const uint4*)&T[cl*72 + rb];
  uint4 v1 = *(const uint4*)&T[cl*72 + rb + 8];
  *(uint4*)(dst + (size_t)(c0 + cl)*512 + r0 + rb) = v0;
  *(uint4*)(dst + (size_t)(c0 + cl)*512 + r0 + rb + 8) = v1;
}

// ---------------- 128x128 GEMM core: D = A * B^T, A rows [M][512], B rows [N][512],
// both bf16 k-fastest. 4 waves, each owns 64x64 (4x4 fragment tiles).
// Staging: global_load_lds w16, source pre-swizzled so ldfrag's XOR layout holds.
__device__ inline void gemm128(const unsigned short* A, const unsigned short* B,
    unsigned short* As, unsigned short* Bs, f32x4 acc[4][4], int tid){
  int lane = tid & 63, w = tid >> 6;
  int wr = w >> 1, wc = w & 1;
  int srow = lane >> 3;
  int scol8 = ((lane & 7) ^ (lane >> 3)) << 3;   // pre-swizzled element offset in row
  for (int k0 = 0; k0 < 512; k0 += 64){
    __syncthreads();
    #pragma unroll
    for (int i = 0; i < 4; i++){
      int r0 = w*32 + i*8;
      gload16(A + (size_t)(r0 + srow)*512 + k0 + scol8, As + r0*64);
      gload16(B + (size_t)(r0 + srow)*512 + k0 + scol8, Bs + r0*64);
    }
    __syncthreads();
    #pragma unroll
    for (int kt = 0; kt < 2; kt++){
      bf16x8 af[4], bfv[4];
      #pragma unroll
      for (int i = 0; i < 4; i++){
        af[i]  = ldfrag(As, wr*64 + i*16 + (lane & 15), kt*64 + ((lane >> 4) << 4));
        bfv[i] = ldfrag(Bs, wc*64 + i*16 + (lane & 15), kt*64 + ((lane >> 4) << 4));
      }
      #pragma unroll
      for (int mi = 0; mi < 4; mi++)
        #pragma unroll
        for (int ni = 0; ni < 4; ni++)
          acc[mi][ni] = __builtin_amdgcn_mfma_f32_16x16x32_bf16(af[mi], bfv[ni], acc[mi][ni], 0,0,0);
    }
  }
}

// ---------------- QK projection: M=1024 s, N=1024 (Q js | K js), per batch
__global__ __launch_bounds__(256) void qk128(const unsigned short* __restrict__ xs,
    const unsigned short* __restrict__ Wqkt, const float* __restrict__ bq,
    const float* __restrict__ bk, unsigned short* __restrict__ q_ws,
    unsigned short* __restrict__ k_ws){
  __shared__ __align__(16) unsigned short As[8192], Bs[8192];
  int tid = threadIdx.x, lane = tid & 63, w = tid >> 6, wr = w >> 1, wc = w & 1;
  int m0 = blockIdx.x * 128, n0 = blockIdx.y * 128, b = blockIdx.z;
  f32x4 acc[4][4];
  #pragma unroll
  for (int i = 0; i < 4; i++)
    #pragma unroll
    for (int j = 0; j < 4; j++) acc[i][j] = (f32x4){0.f,0.f,0.f,0.f};
  gemm128(xs + (size_t)b*S_LEN*CIN + (size_t)m0*512, Wqkt + (size_t)n0*512, As, Bs, acc, tid);
  int jb = (n0 + wc*64) >> 6;          // 0..15
  int isK = jb >= 8, h = jb & 7;
  const float* bias = isK ? bk : bq;
  unsigned short* dst = (isK ? k_ws : q_ws) + ((size_t)(b*NH + h))*S_LEN*DH;
  #pragma unroll
  for (int nt = 0; nt < 4; nt++){
    int d = nt*16 + (lane & 15);
    float bb = bias[(jb & 7)*64 + d];
    #pragma unroll
    for (int mi = 0; mi < 4; mi++)
      #pragma unroll
      for (int r = 0; r < 4; r++){
        int s = m0 + wr*64 + mi*16 + (lane >> 4)*4 + r;
        dst[(size_t)s*DH + d] = f2bf(acc[mi][nt][r] + bb);
      }
  }
}

// ---------------- V^T projection: M=512 j, N=1024 s, per batch -> vt[b][h][d][s]
__global__ __launch_bounds__(256) void vt128(const unsigned short* __restrict__ Wvt,
    const unsigned short* __restrict__ xs, const float* __restrict__ bv,
    unsigned short* __restrict__ vt_ws){
  __shared__ __align__(16) unsigned short As[8192], Bs[8192];
  int tid = threadIdx.x, lane = tid & 63, w = tid >> 6, wr = w >> 1, wc = w & 1;
  int m0 = blockIdx.x * 128, n0 = blockIdx.y * 128, b = blockIdx.z;
  f32x4 acc[4][4];
  #pragma unroll
  for (int i = 0; i < 4; i++)
    #pragma unroll
    for (int j = 0; j < 4; j++) acc[i][j] = (f32x4){0.f,0.f,0.f,0.f};
  gemm128(Wvt + (size_t)m0*512, xs + (size_t)b*S_LEN*CIN + (size_t)n0*512, As, Bs, acc, tid);
  #pragma unroll
  for (int mi = 0; mi < 4; mi++)
    #pragma unroll
    for (int r = 0; r < 4; r++){
      int j = m0 + wr*64 + mi*16 + (lane >> 4)*4 + r;
      int h = j >> 6, dv = j & 63;
      float bb = bv[j];
      unsigned short* dst = vt_ws + ((size_t)(b*NH + h)*DH + dv)*S_LEN;
      #pragma unroll
      for (int nt = 0; nt < 4; nt++){
        int s = n0 + wc*64 + nt*16 + (lane & 15);
        dst[s] = f2bf(acc[mi][nt][r] + bb);
      }
    }
}

// ---------------- flash attention (round-0 proven core, D[dv][q] orientation);
// epilogue transposes O via wave-private LDS -> aw[b][s][j] bf16.
__global__ __launch_bounds__(256) void attn_fwd(const unsigned short* __restrict__ qw,
    const unsigned short* __restrict__ kw, const unsigned short* __restrict__ vtw,
    unsigned short* __restrict__ aw){
  __shared__ __align__(16) unsigned short Ks[4096], Vs[4096], Ps[4096];
  int tid = threadIdx.x, lane = tid & 63, wid = tid >> 6;
  int bid = blockIdx.x;
  int idx = bid >> 3, qb = idx & 15, bh = (bid & 7)*8 + (idx >> 4);  // bh pinned to XCD
  int qrw = lane & 15, g = lane >> 4;
  int q0 = qb*64 + wid*16;
  const unsigned short* qrow = qw + ((size_t)bh*S_LEN + q0 + qrw)*DH;
  bf16x8 qf0 = *(const bf16x8*)(qrow + g*8);
  bf16x8 qf1 = *(const bf16x8*)(qrow + 32 + g*8);
  unsigned short* myP = Ps + wid*1024;
  f32x4 oacc[4];
  #pragma unroll
  for (int i = 0; i < 4; i++) oacc[i] = (f32x4){0.f,0.f,0.f,0.f};
  float mrun = -1e30f, lrun = 0.f;

  for (int kv0 = 0; kv0 < S_LEN; kv0 += 64){
    __syncthreads();
    // stage K tile [64 kcol][64 d] and VT tile [64 d][64 kcol], swizzled b128
    for (int i = tid; i < 512; i += 256){
      int row = i >> 3, ch = i & 7;
      *(uint4*)((char*)Ks + row*128 + ((ch*16) ^ ((row & 7) << 4))) =
          *(const uint4*)(kw + ((size_t)bh*S_LEN + kv0 + row)*DH + ch*8);
      *(uint4*)((char*)Vs + row*128 + ((ch*16) ^ ((row & 7) << 4))) =
          *(const uint4*)(vtw + ((size_t)bh*DH + row)*S_LEN + kv0 + ch*8);
    }
    __syncthreads();

    // S^T tile: D'[kcol][q] via mfma(K, Q)
    f32x4 st[4];
    #pragma unroll
    for (int mt = 0; mt < 4; mt++){
      f32x4 a = (f32x4){0.f,0.f,0.f,0.f};
      a = __builtin_amdgcn_mfma_f32_16x16x32_bf16(
            ldfrag(Ks, mt*16 + qrw, g << 4), qf0, a, 0,0,0);
      a = __builtin_amdgcn_mfma_f32_16x16x32_bf16(
            ldfrag(Ks, mt*16 + qrw, 64 + (g << 4)), qf1, a, 0,0,0);
      st[mt] = a;
    }
    float vmax = -1e30f;
    #pragma unroll
    for (int mt = 0; mt < 4; mt++)
      #pragma unroll
      for (int r = 0; r < 4; r++){
        st[mt][r] *= 0.125f;
        vmax = fmaxf(vmax, st[mt][r]);
      }
    vmax = fmaxf(vmax, __shfl_xor(vmax, 16));
    vmax = fmaxf(vmax, __shfl_xor(vmax, 32));
    float mnew = fmaxf(mrun, vmax);
    float corr = __expf(mrun - mnew);
    float psum = 0.f;
    #pragma unroll
    for (int mt = 0; mt < 4; mt++){
      float p0 = __expf(st[mt][0] - mnew);
      float p1 = __expf(st[mt][1] - mnew);
      float p2 = __expf(st[mt][2] - mnew);
      float p3 = __expf(st[mt][3] - mnew);
      psum += (p0 + p1) + (p2 + p3);
      u16x4 w; w[0]=f2bf(p0); w[1]=f2bf(p1); w[2]=f2bf(p2); w[3]=f2bf(p3);
      *(u16x4*)((char*)myP + qrw*128 + ((mt*32 + g*8) ^ ((qrw & 7) << 4))) = w;
    }
    psum += __shfl_xor(psum, 16);
    psum += __shfl_xor(psum, 32);
    lrun = lrun * corr + psum;
    mrun = mnew;
    #pragma unroll
    for (int mt = 0; mt < 4; mt++) oacc[mt] *= corr;   // col q = qrw: uniform per lane
    // O^T += V^T P^T : mfma(A=VT[dv][k], B=P[q][k]) -> D[dv][q]
    #pragma unroll
    for (int kt = 0; kt < 2; kt++){
      bf16x8 pf = *(const bf16x8*)((char*)myP + qrw*128 +
                    ((kt*64 + (g << 4)) ^ ((qrw & 7) << 4)));
      #pragma unroll
      for (int mt = 0; mt < 4; mt++)
        oacc[mt] = __builtin_amdgcn_mfma_f32_16x16x32_bf16(
            ldfrag(Vs, mt*16 + qrw, kt*64 + (g << 4)), pf, oacc[mt], 0,0,0);
    }
  }
  float inv = 1.f / lrun;   // per q-row = qrw, uniform across g after reduces
  // transpose O within the wave via myP (wave-private; data deps order DS ops):
  // store bf16 O[q_local=qrw][dv], dv = mt*16 + g*4 + r
  #pragma unroll
  for (int mt = 0; mt < 4; mt++)
    #pragma unroll
    for (int r = 0; r < 4; r++){
      int dv = mt*16 + g*4 + r;
      *(unsigned short*)((char*)myP + qrw*128 + ((dv*2) ^ ((qrw & 7) << 4))) =
          f2bf(oacc[mt][r] * inv);
    }
  int b = bh >> 3, h = bh & 7;
  int rr = lane >> 2, cc = lane & 3;   // row q_local, 16-elem chunk
  uint4 lo = *(const uint4*)((char*)myP + rr*128 + ((cc*32) ^ ((rr & 7) << 4)));
  uint4 hi = *(const uint4*)((char*)myP + rr*128 + (((cc*32) + 16) ^ ((rr & 7) << 4)));
  unsigned short* obase = aw + ((size_t)b*S_LEN + (q0 + rr))*512 + h*64 + cc*16;
  *(uint4*)obase = lo;
  *(uint4*)(obase + 8) = hi;
}

// ---------------- out projection: M=512 c, N=1024 s, per batch; + bias + residual
__global__ __launch_bounds__(256) void out128(const unsigned short* __restrict__ Wot,
    const unsigned short* __restrict__ aw, const float* __restrict__ bo,
    const float* __restrict__ x, float* __restrict__ out){
  __shared__ __align__(16) unsigned short As[8192], Bs[8192];
  int tid = threadIdx.x, lane = tid & 63, w = tid >> 6, wr = w >> 1, wc = w & 1;
  int m0 = blockIdx.x * 128, n0 = blockIdx.y * 128, b = blockIdx.z;
  f32x4 acc[4][4];
  #pragma unroll
  for (int i = 0; i < 4; i++)
    #pragma unroll
    for (int j = 0; j < 4; j++) acc[i][j] = (f32x4){0.f,0.f,0.f,0.f};
  gemm128(Wot + (size_t)m0*512, aw + (size_t)b*S_LEN*512 + (size_t)n0*512, As, Bs, acc, tid);
  #pragma unroll
  for (int mi = 0; mi < 4; mi++)
    #pragma unroll
    for (int r = 0; r < 4; r++){
      int c = m0 + wr*64 + mi*16 + (lane >> 4)*4 + r;
      float bb = bo[c];
      size_t rowb = ((size_t)b*CIN + c)*S_LEN;
      #pragma unroll
      for (int nt = 0; nt < 4; nt++){
        int s = n0 + wc*64 + nt*16 + (lane & 15);
        out[rowb + s] = acc[mi][nt][r] + bb + x[rowb + s];
      }
    }
}

extern "C" void kernel_launch(void* const* d_in, const int* in_sizes, int n_in,
                              void* d_out, int out_size, void* d_ws, size_t ws_size,
                              hipStream_t stream){
  const float* x  = (const float*)d_in[0];
  const float* Wq = (const float*)d_in[1];
  const float* bq = (const float*)d_in[2];
  const float* Wk = (const float*)d_in[3];
  const float* bk = (const float*)d_in[4];
  const float* Wv = (const float*)d_in[5];
  const float* bv = (const float*)d_in[6];
  const float* Wo = (const float*)d_in[7];
  const float* bo = (const float*)d_in[8];
  float* out = (float*)d_out;

  unsigned short* p = (unsigned short*)d_ws;
  const size_t xs_e   = (size_t)NB*S_LEN*CIN;        // 4.19M
  const size_t qkv_e  = (size_t)NB*NH*S_LEN*DH;      // 4.19M
  unsigned short* xs    = p;                 p += xs_e;
  unsigned short* Wqkt  = p;                 p += 1024*512;
  unsigned short* Wvt   = p;                 p += 512*512;
  unsigned short* Wot   = p;                 p += 512*512;
  unsigned short* q_ws  = p;                 p += qkv_e;
  unsigned short* k_ws  = p;                 p += qkv_e;
  unsigned short* vt_ws = p;                 p += qkv_e;
  unsigned short* aw    = p;                 p += qkv_e;   // [b][s][512] bf16

  prep<<<1280, 256, 0, stream>>>(x, Wq, Wk, Wv, Wo, xs, Wqkt, Wvt, Wot);
  qk128<<<dim3(8, 8, NB), 256, 0, stream>>>(xs, Wqkt, bq, bk, q_ws, k_ws);
  vt128<<<dim3(4, 8, NB), 256, 0, stream>>>(Wvt, xs, bv, vt_ws);
  attn_fwd<<<1024, 256, 0, stream>>>(q_ws, k_ws, vt_ws, aw);
  out128<<<dim3(4, 8, NB), 256, 0, stream>>>(Wot, aw, bo, x, out);
}

// Round 7
// 163.390 us; speedup vs baseline: 1.3222x; 1.0317x over previous
//
#include <hip/hip_runtime.h>

#define S_LEN 1024
#define CIN 512
#define NH 8
#define DH 64
#define NB 8

typedef short bf16x8 __attribute__((ext_vector_type(8)));
typedef float f32x4 __attribute__((ext_vector_type(4)));
typedef unsigned short u16x4 __attribute__((ext_vector_type(4)));

__device__ inline unsigned short f2bf(float f){
  union { float f; unsigned u; } v; v.f = f;
  unsigned r = v.u + 0x7FFFu + ((v.u >> 16) & 1u);
  return (unsigned short)(r >> 16);
}

// async global->LDS, 16B per lane. LDS dest = base + lane*16 (wave-uniform base).
__device__ inline void gload16(const void* g, void* l){
  __builtin_amdgcn_global_load_lds(
      (const __attribute__((address_space(1))) unsigned*)g,
      (__attribute__((address_space(3))) unsigned*)l, 16, 0, 0);
}

// swizzled frag read from LDS tile with 128B rows: phys col = kbyte ^ ((row&7)<<4)
__device__ inline bf16x8 ldfrag(const unsigned short* lds, int row, int kbyte){
  return *(const bf16x8*)((const char*)lds + row*128 + (kbyte ^ ((row & 7) << 4)));
}

// ---------------- prep: transpose+convert fp32 -> bf16 (64x64 tiles) ----------------
// blocks 0..1023: x[b][c][s] -> xs[b][s][c]; 1024..1279: the 4 weight matrices.
__global__ __launch_bounds__(256) void prep(const float* __restrict__ x,
    const float* __restrict__ Wq, const float* __restrict__ Wk,
    const float* __restrict__ Wv, const float* __restrict__ Wo,
    unsigned short* __restrict__ xs, unsigned short* __restrict__ Wqkt,
    unsigned short* __restrict__ Wvt, unsigned short* __restrict__ Wot){
  __shared__ unsigned short T[64*72];
  int bid = blockIdx.x, t = threadIdx.x;
  const float* src; unsigned short* dst; int ldS, r0, c0;
  if (bid < 1024){
    int b = bid >> 7, tt = bid & 127;
    src = x + (size_t)b*CIN*S_LEN; ldS = S_LEN;
    dst = xs + (size_t)b*S_LEN*CIN;
    r0 = (tt >> 4) * 64;            // c
    c0 = (tt & 15) * 64;            // s
  } else {
    int w = bid - 1024, mat = w >> 6, tt = w & 63;
    r0 = (tt >> 3) * 64; c0 = (tt & 7) * 64; ldS = 512;
    if (mat == 0){ src = Wq; dst = Wqkt; }
    else if (mat == 1){ src = Wk; dst = Wqkt + 512*512; }
    else if (mat == 2){ src = Wv; dst = Wvt; }
    else            { src = Wo; dst = Wot; }
  }
  int rl = t >> 4, cb = (t & 15) * 4;
  #pragma unroll
  for (int rr = 0; rr < 4; rr++){
    float4 f = *(const float4*)(src + (size_t)(r0 + rl + rr*16)*ldS + c0 + cb);
    int rc = rl + rr*16;
    T[(cb+0)*72 + rc] = f2bf(f.x);
    T[(cb+1)*72 + rc] = f2bf(f.y);
    T[(cb+2)*72 + rc] = f2bf(f.z);
    T[(cb+3)*72 + rc] = f2bf(f.w);
  }
  __syncthreads();
  // write-back: each thread copies its FULL 16-element strip (2 x uint4).
  int cl = t >> 2, rb = (t & 3) * 16;
  uint4 v0 = *(const uint4*)&T[cl*72 + rb];
  uint4 v1 = *(const uint4*)&T[cl*72 + rb + 8];
  *(uint4*)(dst + (size_t)(c0 + cl)*512 + r0 + rb) = v0;
  *(uint4*)(dst + (size_t)(c0 + cl)*512 + r0 + rb + 8) = v1;
}

// ---------------- 128x128 GEMM core: D = A * B^T, A rows [M][512], B rows [N][512],
// both bf16 k-fastest. 4 waves, each owns 64x64 (4x4 fragment tiles).
// Staging: global_load_lds w16, source pre-swizzled so ldfrag's XOR layout holds.
__device__ inline void gemm128(const unsigned short* A, const unsigned short* B,
    unsigned short* As, unsigned short* Bs, f32x4 acc[4][4], int tid){
  int lane = tid & 63, w = tid >> 6;
  int wr = w >> 1, wc = w & 1;
  int srow = lane >> 3;
  int scol8 = ((lane & 7) ^ (lane >> 3)) << 3;   // pre-swizzled element offset in row
  for (int k0 = 0; k0 < 512; k0 += 64){
    __syncthreads();
    #pragma unroll
    for (int i = 0; i < 4; i++){
      int r0 = w*32 + i*8;
      gload16(A + (size_t)(r0 + srow)*512 + k0 + scol8, As + r0*64);
      gload16(B + (size_t)(r0 + srow)*512 + k0 + scol8, Bs + r0*64);
    }
    __syncthreads();
    #pragma unroll
    for (int kt = 0; kt < 2; kt++){
      bf16x8 af[4], bfv[4];
      #pragma unroll
      for (int i = 0; i < 4; i++){
        af[i]  = ldfrag(As, wr*64 + i*16 + (lane & 15), kt*64 + ((lane >> 4) << 4));
        bfv[i] = ldfrag(Bs, wc*64 + i*16 + (lane & 15), kt*64 + ((lane >> 4) << 4));
      }
      #pragma unroll
      for (int mi = 0; mi < 4; mi++)
        #pragma unroll
        for (int ni = 0; ni < 4; ni++)
          acc[mi][ni] = __builtin_amdgcn_mfma_f32_16x16x32_bf16(af[mi], bfv[ni], acc[mi][ni], 0,0,0);
    }
  }
}

// ---------------- merged QKV projection, per batch.
// blockIdx.y 0..7:  Q|K  (M = s block x, N = js block y)
// blockIdx.y 8..11: V^T  (M = j block y-8, N = s block x)
__global__ __launch_bounds__(256) void qkv128(const unsigned short* __restrict__ xs,
    const unsigned short* __restrict__ Wqkt, const unsigned short* __restrict__ Wvt,
    const float* __restrict__ bq, const float* __restrict__ bk,
    const float* __restrict__ bv, unsigned short* __restrict__ q_ws,
    unsigned short* __restrict__ k_ws, unsigned short* __restrict__ vt_ws){
  __shared__ __align__(16) unsigned short As[8192], Bs[8192];
  int tid = threadIdx.x, lane = tid & 63, w = tid >> 6, wr = w >> 1, wc = w & 1;
  int bx = blockIdx.x, by = blockIdx.y, b = blockIdx.z;
  f32x4 acc[4][4];
  #pragma unroll
  for (int i = 0; i < 4; i++)
    #pragma unroll
    for (int j = 0; j < 4; j++) acc[i][j] = (f32x4){0.f,0.f,0.f,0.f};
  if (by < 8){
    int m0 = bx * 128, n0 = by * 128;
    gemm128(xs + (size_t)b*S_LEN*CIN + (size_t)m0*512, Wqkt + (size_t)n0*512, As, Bs, acc, tid);
    int jb = (n0 + wc*64) >> 6;          // 0..15
    int isK = jb >= 8, h = jb & 7;
    const float* bias = isK ? bk : bq;
    unsigned short* dst = (isK ? k_ws : q_ws) + ((size_t)(b*NH + h))*S_LEN*DH;
    #pragma unroll
    for (int nt = 0; nt < 4; nt++){
      int d = nt*16 + (lane & 15);
      float bb = bias[(jb & 7)*64 + d];
      #pragma unroll
      for (int mi = 0; mi < 4; mi++)
        #pragma unroll
        for (int r = 0; r < 4; r++){
          int s = m0 + wr*64 + mi*16 + (lane >> 4)*4 + r;
          dst[(size_t)s*DH + d] = f2bf(acc[mi][nt][r] + bb);
        }
    }
  } else {
    int m0 = (by - 8) * 128, n0 = bx * 128;
    gemm128(Wvt + (size_t)m0*512, xs + (size_t)b*S_LEN*CIN + (size_t)n0*512, As, Bs, acc, tid);
    #pragma unroll
    for (int mi = 0; mi < 4; mi++)
      #pragma unroll
      for (int r = 0; r < 4; r++){
        int j = m0 + wr*64 + mi*16 + (lane >> 4)*4 + r;
        int h = j >> 6, dv = j & 63;
        float bb = bv[j];
        unsigned short* dst = vt_ws + ((size_t)(b*NH + h)*DH + dv)*S_LEN;
        #pragma unroll
        for (int nt = 0; nt < 4; nt++){
          int s = n0 + wc*64 + nt*16 + (lane & 15);
          dst[s] = f2bf(acc[mi][nt][r] + bb);
        }
      }
  }
}

// ---------------- flash attention (proven core; gload16 staging; exp2 softmax);
// epilogue transposes O via wave-private LDS -> aw[b][s][j] bf16.
__global__ __launch_bounds__(256) void attn_fwd(const unsigned short* __restrict__ qw,
    const unsigned short* __restrict__ kw, const unsigned short* __restrict__ vtw,
    unsigned short* __restrict__ aw){
  __shared__ __align__(16) unsigned short Ks[4096], Vs[4096], Ps[4096];
  int tid = threadIdx.x, lane = tid & 63, wid = tid >> 6;
  int bid = blockIdx.x;
  int idx = bid >> 3, qb = idx & 15, bh = (bid & 7)*8 + (idx >> 4);  // bh pinned to XCD
  int qrw = lane & 15, g = lane >> 4;
  int q0 = qb*64 + wid*16;
  const unsigned short* qrow = qw + ((size_t)bh*S_LEN + q0 + qrw)*DH;
  bf16x8 qf0 = *(const bf16x8*)(qrow + g*8);
  bf16x8 qf1 = *(const bf16x8*)(qrow + 32 + g*8);
  unsigned short* myP = Ps + wid*1024;
  f32x4 oacc[4];
  #pragma unroll
  for (int i = 0; i < 4; i++) oacc[i] = (f32x4){0.f,0.f,0.f,0.f};
  float mrun = -3e38f, lrun = 0.f;
  int srow = lane >> 3, scol8 = ((lane & 7) ^ (lane >> 3)) << 3;
  const unsigned short* kbase = kw + (size_t)bh*S_LEN*DH;
  const unsigned short* vbase = vtw + (size_t)bh*DH*S_LEN;
  const float SC = 0.125f * 1.44269504f;   // scale * log2(e): softmax in exp2 domain

  for (int kv0 = 0; kv0 < S_LEN; kv0 += 64){
    __syncthreads();
    // stage K tile [64 kcol][64 d] and VT tile [64 dv][64 kcol] via global_load_lds
    #pragma unroll
    for (int i = 0; i < 2; i++){
      int r0 = wid*16 + i*8;
      gload16(kbase + (size_t)(kv0 + r0 + srow)*DH + scol8, Ks + r0*64);
      gload16(vbase + (size_t)(r0 + srow)*S_LEN + kv0 + scol8, Vs + r0*64);
    }
    __syncthreads();

    // S^T tile: D'[kcol][q] via mfma(K, Q)
    f32x4 st[4];
    #pragma unroll
    for (int mt = 0; mt < 4; mt++){
      f32x4 a = (f32x4){0.f,0.f,0.f,0.f};
      a = __builtin_amdgcn_mfma_f32_16x16x32_bf16(
            ldfrag(Ks, mt*16 + qrw, g << 4), qf0, a, 0,0,0);
      a = __builtin_amdgcn_mfma_f32_16x16x32_bf16(
            ldfrag(Ks, mt*16 + qrw, 64 + (g << 4)), qf1, a, 0,0,0);
      st[mt] = a;
    }
    float vmax = -3e38f;
    #pragma unroll
    for (int mt = 0; mt < 4; mt++)
      #pragma unroll
      for (int r = 0; r < 4; r++){
        st[mt][r] *= SC;
        vmax = fmaxf(vmax, st[mt][r]);
      }
    vmax = fmaxf(vmax, __shfl_xor(vmax, 16));
    vmax = fmaxf(vmax, __shfl_xor(vmax, 32));
    float mnew = fmaxf(mrun, vmax);
    float corr = __builtin_amdgcn_exp2f(mrun - mnew);
    float psum = 0.f;
    #pragma unroll
    for (int mt = 0; mt < 4; mt++){
      float p0 = __builtin_amdgcn_exp2f(st[mt][0] - mnew);
      float p1 = __builtin_amdgcn_exp2f(st[mt][1] - mnew);
      float p2 = __builtin_amdgcn_exp2f(st[mt][2] - mnew);
      float p3 = __builtin_amdgcn_exp2f(st[mt][3] - mnew);
      psum += (p0 + p1) + (p2 + p3);
      u16x4 w; w[0]=f2bf(p0); w[1]=f2bf(p1); w[2]=f2bf(p2); w[3]=f2bf(p3);
      *(u16x4*)((char*)myP + qrw*128 + ((mt*32 + g*8) ^ ((qrw & 7) << 4))) = w;
    }
    psum += __shfl_xor(psum, 16);
    psum += __shfl_xor(psum, 32);
    lrun = lrun * corr + psum;
    mrun = mnew;
    #pragma unroll
    for (int mt = 0; mt < 4; mt++) oacc[mt] *= corr;   // col q = qrw: uniform per lane
    // O^T += V^T P^T : mfma(A=VT[dv][k], B=P[q][k]) -> D[dv][q]
    #pragma unroll
    for (int kt = 0; kt < 2; kt++){
      bf16x8 pf = *(const bf16x8*)((char*)myP + qrw*128 +
                    ((kt*64 + (g << 4)) ^ ((qrw & 7) << 4)));
      #pragma unroll
      for (int mt = 0; mt < 4; mt++)
        oacc[mt] = __builtin_amdgcn_mfma_f32_16x16x32_bf16(
            ldfrag(Vs, mt*16 + qrw, kt*64 + (g << 4)), pf, oacc[mt], 0,0,0);
    }
  }
  float inv = 1.f / lrun;   // per q-row = qrw, uniform across g after reduces
  // transpose O within the wave via myP (wave-private; data deps order DS ops):
  // store bf16 O[q_local=qrw][dv], dv = mt*16 + g*4 + r
  #pragma unroll
  for (int mt = 0; mt < 4; mt++)
    #pragma unroll
    for (int r = 0; r < 4; r++){
      int dv = mt*16 + g*4 + r;
      *(unsigned short*)((char*)myP + qrw*128 + ((dv*2) ^ ((qrw & 7) << 4))) =
          f2bf(oacc[mt][r] * inv);
    }
  int b = bh >> 3, h = bh & 7;
  int rr = lane >> 2, cc = lane & 3;   // row q_local, 16-elem chunk
  uint4 lo = *(const uint4*)((char*)myP + rr*128 + ((cc*32) ^ ((rr & 7) << 4)));
  uint4 hi = *(const uint4*)((char*)myP + rr*128 + (((cc*32) + 16) ^ ((rr & 7) << 4)));
  unsigned short* obase = aw + ((size_t)b*S_LEN + (q0 + rr))*512 + h*64 + cc*16;
  *(uint4*)obase = lo;
  *(uint4*)(obase + 8) = hi;
}

// ---------------- out projection: M=512 c, N=1024 s, per batch; + bias + residual
__global__ __launch_bounds__(256) void out128(const unsigned short* __restrict__ Wot,
    const unsigned short* __restrict__ aw, const float* __restrict__ bo,
    const float* __restrict__ x, float* __restrict__ out){
  __shared__ __align__(16) unsigned short As[8192], Bs[8192];
  int tid = threadIdx.x, lane = tid & 63, w = tid >> 6, wr = w >> 1, wc = w & 1;
  int m0 = blockIdx.x * 128, n0 = blockIdx.y * 128, b = blockIdx.z;
  f32x4 acc[4][4];
  #pragma unroll
  for (int i = 0; i < 4; i++)
    #pragma unroll
    for (int j = 0; j < 4; j++) acc[i][j] = (f32x4){0.f,0.f,0.f,0.f};
  gemm128(Wot + (size_t)m0*512, aw + (size_t)b*S_LEN*512 + (size_t)n0*512, As, Bs, acc, tid);
  #pragma unroll
  for (int mi = 0; mi < 4; mi++)
    #pragma unroll
    for (int r = 0; r < 4; r++){
      int c = m0 + wr*64 + mi*16 + (lane >> 4)*4 + r;
      float bb = bo[c];
      size_t rowb = ((size_t)b*CIN + c)*S_LEN;
      #pragma unroll
      for (int nt = 0; nt < 4; nt++){
        int s = n0 + wc*64 + nt*16 + (lane & 15);
        out[rowb + s] = acc[mi][nt][r] + bb + x[rowb + s];
      }
    }
}

extern "C" void kernel_launch(void* const* d_in, const int* in_sizes, int n_in,
                              void* d_out, int out_size, void* d_ws, size_t ws_size,
                              hipStream_t stream){
  const float* x  = (const float*)d_in[0];
  const float* Wq = (const float*)d_in[1];
  const float* bq = (const float*)d_in[2];
  const float* Wk = (const float*)d_in[3];
  const float* bk = (const float*)d_in[4];
  const float* Wv = (const float*)d_in[5];
  const float* bv = (const float*)d_in[6];
  const float* Wo = (const float*)d_in[7];
  const float* bo = (const float*)d_in[8];
  float* out = (float*)d_out;

  unsigned short* p = (unsigned short*)d_ws;
  const size_t xs_e   = (size_t)NB*S_LEN*CIN;        // 4.19M
  const size_t qkv_e  = (size_t)NB*NH*S_LEN*DH;      // 4.19M
  unsigned short* xs    = p;                 p += xs_e;
  unsigned short* Wqkt  = p;                 p += 1024*512;
  unsigned short* Wvt   = p;                 p += 512*512;
  unsigned short* Wot   = p;                 p += 512*512;
  unsigned short* q_ws  = p;                 p += qkv_e;
  unsigned short* k_ws  = p;                 p += qkv_e;
  unsigned short* vt_ws = p;                 p += qkv_e;
  unsigned short* aw    = p;                 p += qkv_e;   // [b][s][512] bf16

  prep<<<1280, 256, 0, stream>>>(x, Wq, Wk, Wv, Wo, xs, Wqkt, Wvt, Wot);
  qkv128<<<dim3(8, 12, NB), 256, 0, stream>>>(xs, Wqkt, Wvt, bq, bk, bv, q_ws, k_ws, vt_ws);
  attn_fwd<<<1024, 256, 0, stream>>>(q_ws, k_ws, vt_ws, aw);
  out128<<<dim3(4, 8, NB), 256, 0, stream>>>(Wot, aw, bo, x, out);
}

// Round 8
// 156.530 us; speedup vs baseline: 1.3802x; 1.0438x over previous
//
#include <hip/hip_runtime.h>

#define S_LEN 1024
#define CIN 512
#define NH 8
#define DH 64
#define NB 8

typedef short bf16x8 __attribute__((ext_vector_type(8)));
typedef float f32x4 __attribute__((ext_vector_type(4)));
typedef unsigned short u16x4 __attribute__((ext_vector_type(4)));

__device__ inline unsigned short f2bf(float f){
  union { float f; unsigned u; } v; v.f = f;
  unsigned r = v.u + 0x7FFFu + ((v.u >> 16) & 1u);
  return (unsigned short)(r >> 16);
}

// packed f32x2 -> bf16x2 (RNE, same numerics as f2bf), T12 recipe
__device__ inline unsigned cvt_pk_bf16(float a, float b){
  unsigned r;
  asm("v_cvt_pk_bf16_f32 %0, %1, %2" : "=v"(r) : "v"(a), "v"(b));
  return r;
}

// async global->LDS, 16B per lane. LDS dest = base + lane*16 (wave-uniform base).
__device__ inline void gload16(const void* g, void* l){
  __builtin_amdgcn_global_load_lds(
      (const __attribute__((address_space(1))) unsigned*)g,
      (__attribute__((address_space(3))) unsigned*)l, 16, 0, 0);
}

// swizzled frag read from LDS tile with 128B rows: phys col = kbyte ^ ((row&7)<<4)
__device__ inline bf16x8 ldfrag(const unsigned short* lds, int row, int kbyte){
  return *(const bf16x8*)((const char*)lds + row*128 + (kbyte ^ ((row & 7) << 4)));
}

// ---------------- prep: transpose+convert fp32 -> bf16 (64x64 tiles) ----------------
__global__ __launch_bounds__(256) void prep(const float* __restrict__ x,
    const float* __restrict__ Wq, const float* __restrict__ Wk,
    const float* __restrict__ Wv, const float* __restrict__ Wo,
    unsigned short* __restrict__ xs, unsigned short* __restrict__ Wqkt,
    unsigned short* __restrict__ Wvt, unsigned short* __restrict__ Wot){
  __shared__ unsigned short T[64*72];
  int bid = blockIdx.x, t = threadIdx.x;
  const float* src; unsigned short* dst; int ldS, r0, c0;
  if (bid < 1024){
    int b = bid >> 7, tt = bid & 127;
    src = x + (size_t)b*CIN*S_LEN; ldS = S_LEN;
    dst = xs + (size_t)b*S_LEN*CIN;
    r0 = (tt >> 4) * 64;            // c
    c0 = (tt & 15) * 64;            // s
  } else {
    int w = bid - 1024, mat = w >> 6, tt = w & 63;
    r0 = (tt >> 3) * 64; c0 = (tt & 7) * 64; ldS = 512;
    if (mat == 0){ src = Wq; dst = Wqkt; }
    else if (mat == 1){ src = Wk; dst = Wqkt + 512*512; }
    else if (mat == 2){ src = Wv; dst = Wvt; }
    else            { src = Wo; dst = Wot; }
  }
  int rl = t >> 4, cb = (t & 15) * 4;
  #pragma unroll
  for (int rr = 0; rr < 4; rr++){
    float4 f = *(const float4*)(src + (size_t)(r0 + rl + rr*16)*ldS + c0 + cb);
    int rc = rl + rr*16;
    T[(cb+0)*72 + rc] = f2bf(f.x);
    T[(cb+1)*72 + rc] = f2bf(f.y);
    T[(cb+2)*72 + rc] = f2bf(f.z);
    T[(cb+3)*72 + rc] = f2bf(f.w);
  }
  __syncthreads();
  int cl = t >> 2, rb = (t & 3) * 16;
  uint4 v0 = *(const uint4*)&T[cl*72 + rb];
  uint4 v1 = *(const uint4*)&T[cl*72 + rb + 8];
  *(uint4*)(dst + (size_t)(c0 + cl)*512 + r0 + rb) = v0;
  *(uint4*)(dst + (size_t)(c0 + cl)*512 + r0 + rb + 8) = v1;
}

// ---------------- 128x128 GEMM core: D = A * B^T (unchanged, m97-style) ----------------
__device__ inline void gemm128(const unsigned short* A, const unsigned short* B,
    unsigned short* As, unsigned short* Bs, f32x4 acc[4][4], int tid){
  int lane = tid & 63, w = tid >> 6;
  int wr = w >> 1, wc = w & 1;
  int srow = lane >> 3;
  int scol8 = ((lane & 7) ^ (lane >> 3)) << 3;   // pre-swizzled element offset in row
  for (int k0 = 0; k0 < 512; k0 += 64){
    __syncthreads();
    #pragma unroll
    for (int i = 0; i < 4; i++){
      int r0 = w*32 + i*8;
      gload16(A + (size_t)(r0 + srow)*512 + k0 + scol8, As + r0*64);
      gload16(B + (size_t)(r0 + srow)*512 + k0 + scol8, Bs + r0*64);
    }
    __syncthreads();
    #pragma unroll
    for (int kt = 0; kt < 2; kt++){
      bf16x8 af[4], bfv[4];
      #pragma unroll
      for (int i = 0; i < 4; i++){
        af[i]  = ldfrag(As, wr*64 + i*16 + (lane & 15), kt*64 + ((lane >> 4) << 4));
        bfv[i] = ldfrag(Bs, wc*64 + i*16 + (lane & 15), kt*64 + ((lane >> 4) << 4));
      }
      #pragma unroll
      for (int mi = 0; mi < 4; mi++)
        #pragma unroll
        for (int ni = 0; ni < 4; ni++)
          acc[mi][ni] = __builtin_amdgcn_mfma_f32_16x16x32_bf16(af[mi], bfv[ni], acc[mi][ni], 0,0,0);
    }
  }
}

// ---------------- merged QKV projection (unchanged) ----------------
__global__ __launch_bounds__(256) void qkv128(const unsigned short* __restrict__ xs,
    const unsigned short* __restrict__ Wqkt, const unsigned short* __restrict__ Wvt,
    const float* __restrict__ bq, const float* __restrict__ bk,
    const float* __restrict__ bv, unsigned short* __restrict__ q_ws,
    unsigned short* __restrict__ k_ws, unsigned short* __restrict__ vt_ws){
  __shared__ __align__(16) unsigned short As[8192], Bs[8192];
  int tid = threadIdx.x, lane = tid & 63, w = tid >> 6, wr = w >> 1, wc = w & 1;
  int bx = blockIdx.x, by = blockIdx.y, b = blockIdx.z;
  f32x4 acc[4][4];
  #pragma unroll
  for (int i = 0; i < 4; i++)
    #pragma unroll
    for (int j = 0; j < 4; j++) acc[i][j] = (f32x4){0.f,0.f,0.f,0.f};
  if (by < 8){
    int m0 = bx * 128, n0 = by * 128;
    gemm128(xs + (size_t)b*S_LEN*CIN + (size_t)m0*512, Wqkt + (size_t)n0*512, As, Bs, acc, tid);
    int jb = (n0 + wc*64) >> 6;          // 0..15
    int isK = jb >= 8, h = jb & 7;
    const float* bias = isK ? bk : bq;
    unsigned short* dst = (isK ? k_ws : q_ws) + ((size_t)(b*NH + h))*S_LEN*DH;
    #pragma unroll
    for (int nt = 0; nt < 4; nt++){
      int d = nt*16 + (lane & 15);
      float bb = bias[(jb & 7)*64 + d];
      #pragma unroll
      for (int mi = 0; mi < 4; mi++)
        #pragma unroll
        for (int r = 0; r < 4; r++){
          int s = m0 + wr*64 + mi*16 + (lane >> 4)*4 + r;
          dst[(size_t)s*DH + d] = f2bf(acc[mi][nt][r] + bb);
        }
    }
  } else {
    int m0 = (by - 8) * 128, n0 = bx * 128;
    gemm128(Wvt + (size_t)m0*512, xs + (size_t)b*S_LEN*CIN + (size_t)n0*512, As, Bs, acc, tid);
    #pragma unroll
    for (int mi = 0; mi < 4; mi++)
      #pragma unroll
      for (int r = 0; r < 4; r++){
        int j = m0 + wr*64 + mi*16 + (lane >> 4)*4 + r;
        int h = j >> 6, dv = j & 63;
        float bb = bv[j];
        unsigned short* dst = vt_ws + ((size_t)(b*NH + h)*DH + dv)*S_LEN;
        #pragma unroll
        for (int nt = 0; nt < 4; nt++){
          int s = n0 + wc*64 + nt*16 + (lane & 15);
          dst[s] = f2bf(acc[mi][nt][r] + bb);
        }
      }
  }
}

// ---------------- flash attention: 8 waves / 128 q-rows per block, dbuf K/V,
// packed P/O stores. Core fragment math identical to the proven round-6 kernel.
__global__ __launch_bounds__(512) void attn_fwd(const unsigned short* __restrict__ qw,
    const unsigned short* __restrict__ kw, const unsigned short* __restrict__ vtw,
    unsigned short* __restrict__ aw){
  __shared__ __align__(16) unsigned short Ks[2][4096], Vs[2][4096], Ps[8192];
  int tid = threadIdx.x, lane = tid & 63, wid = tid >> 6;   // wid 0..7
  int bid = blockIdx.x;                 // 512 blocks
  int idx = bid >> 3;                   // 0..63
  int qb = idx & 7;                     // q block (128 rows)
  int bh = (bid & 7)*8 + (idx >> 3);    // bh pinned to XCD
  int qrw = lane & 15, g = lane >> 4;
  int q0 = qb*128 + wid*16;
  const unsigned short* qrow = qw + ((size_t)bh*S_LEN + q0 + qrw)*DH;
  bf16x8 qf0 = *(const bf16x8*)(qrow + g*8);
  bf16x8 qf1 = *(const bf16x8*)(qrow + 32 + g*8);
  unsigned short* myP = Ps + wid*1024;
  f32x4 oacc[4];
  #pragma unroll
  for (int i = 0; i < 4; i++) oacc[i] = (f32x4){0.f,0.f,0.f,0.f};
  float mrun = -3e38f, lrun = 0.f;
  int srow = lane >> 3, scol8 = ((lane & 7) ^ (lane >> 3)) << 3;
  const unsigned short* kbase = kw + (size_t)bh*S_LEN*DH;
  const unsigned short* vbase = vtw + (size_t)bh*DH*S_LEN;
  const float SC = 0.125f * 1.44269504f;   // scale * log2(e)
  int r0 = wid*8;                          // this wave's 8 staging rows
  // prologue: stage tile 0 into buffer 0 (each wave stages 8 rows of K and V)
  gload16(kbase + (size_t)(r0 + srow)*DH + scol8, Ks[0] + r0*64);
  gload16(vbase + (size_t)(r0 + srow)*S_LEN + scol8, Vs[0] + r0*64);
  __syncthreads();
  int cur = 0;

  for (int kv0 = 0; kv0 < S_LEN; kv0 += 64){
    // issue next tile's loads into the alternate buffer BEFORE computing
    if (kv0 + 64 < S_LEN){
      gload16(kbase + (size_t)(kv0 + 64 + r0 + srow)*DH + scol8, Ks[cur^1] + r0*64);
      gload16(vbase + (size_t)(r0 + srow)*S_LEN + kv0 + 64 + scol8, Vs[cur^1] + r0*64);
    }
    const unsigned short* Kc = Ks[cur];
    const unsigned short* Vc = Vs[cur];

    // S^T tile: D'[kcol][q] via mfma(K, Q)
    f32x4 st[4];
    #pragma unroll
    for (int mt = 0; mt < 4; mt++){
      f32x4 a = (f32x4){0.f,0.f,0.f,0.f};
      a = __builtin_amdgcn_mfma_f32_16x16x32_bf16(
            ldfrag(Kc, mt*16 + qrw, g << 4), qf0, a, 0,0,0);
      a = __builtin_amdgcn_mfma_f32_16x16x32_bf16(
            ldfrag(Kc, mt*16 + qrw, 64 + (g << 4)), qf1, a, 0,0,0);
      st[mt] = a;
    }
    float vmax = -3e38f;
    #pragma unroll
    for (int mt = 0; mt < 4; mt++)
      #pragma unroll
      for (int r = 0; r < 4; r++){
        st[mt][r] *= SC;
        vmax = fmaxf(vmax, st[mt][r]);
      }
    vmax = fmaxf(vmax, __shfl_xor(vmax, 16));
    vmax = fmaxf(vmax, __shfl_xor(vmax, 32));
    float mnew = fmaxf(mrun, vmax);
    float corr = __builtin_amdgcn_exp2f(mrun - mnew);
    float psum = 0.f;
    #pragma unroll
    for (int mt = 0; mt < 4; mt++){
      float p0 = __builtin_amdgcn_exp2f(st[mt][0] - mnew);
      float p1 = __builtin_amdgcn_exp2f(st[mt][1] - mnew);
      float p2 = __builtin_amdgcn_exp2f(st[mt][2] - mnew);
      float p3 = __builtin_amdgcn_exp2f(st[mt][3] - mnew);
      psum += (p0 + p1) + (p2 + p3);
      uint2 pw; pw.x = cvt_pk_bf16(p0, p1); pw.y = cvt_pk_bf16(p2, p3);
      *(uint2*)((char*)myP + qrw*128 + ((mt*32 + g*8) ^ ((qrw & 7) << 4))) = pw;
    }
    psum += __shfl_xor(psum, 16);
    psum += __shfl_xor(psum, 32);
    lrun = lrun * corr + psum;
    mrun = mnew;
    #pragma unroll
    for (int mt = 0; mt < 4; mt++) oacc[mt] *= corr;   // col q = qrw: uniform per lane
    // O^T += V^T P^T : mfma(A=VT[dv][k], B=P[q][k]) -> D[dv][q]
    #pragma unroll
    for (int kt = 0; kt < 2; kt++){
      bf16x8 pf = *(const bf16x8*)((char*)myP + qrw*128 +
                    ((kt*64 + (g << 4)) ^ ((qrw & 7) << 4)));
      #pragma unroll
      for (int mt = 0; mt < 4; mt++)
        oacc[mt] = __builtin_amdgcn_mfma_f32_16x16x32_bf16(
            ldfrag(Vc, mt*16 + qrw, kt*64 + (g << 4)), pf, oacc[mt], 0,0,0);
    }
    __syncthreads();   // next tile staged (vmcnt drained) + everyone done with cur
    cur ^= 1;
  }
  float inv = 1.f / lrun;   // per q-row = qrw, uniform across g after reduces
  // transpose O within the wave via myP (wave-private): O[q_local=qrw][dv], packed
  #pragma unroll
  for (int mt = 0; mt < 4; mt++){
    uint2 pw;
    pw.x = cvt_pk_bf16(oacc[mt][0] * inv, oacc[mt][1] * inv);
    pw.y = cvt_pk_bf16(oacc[mt][2] * inv, oacc[mt][3] * inv);
    *(uint2*)((char*)myP + qrw*128 + ((mt*32 + g*8) ^ ((qrw & 7) << 4))) = pw;
  }
  int b = bh >> 3, h = bh & 7;
  int rr = lane >> 2, cc = lane & 3;   // row q_local, 16-elem chunk
  uint4 lo = *(const uint4*)((char*)myP + rr*128 + ((cc*32) ^ ((rr & 7) << 4)));
  uint4 hi = *(const uint4*)((char*)myP + rr*128 + (((cc*32) + 16) ^ ((rr & 7) << 4)));
  unsigned short* obase = aw + ((size_t)b*S_LEN + (q0 + rr))*512 + h*64 + cc*16;
  *(uint4*)obase = lo;
  *(uint4*)(obase + 8) = hi;
}

// ---------------- out projection (unchanged) ----------------
__global__ __launch_bounds__(256) void out128(const unsigned short* __restrict__ Wot,
    const unsigned short* __restrict__ aw, const float* __restrict__ bo,
    const float* __restrict__ x, float* __restrict__ out){
  __shared__ __align__(16) unsigned short As[8192], Bs[8192];
  int tid = threadIdx.x, lane = tid & 63, w = tid >> 6, wr = w >> 1, wc = w & 1;
  int m0 = blockIdx.x * 128, n0 = blockIdx.y * 128, b = blockIdx.z;
  f32x4 acc[4][4];
  #pragma unroll
  for (int i = 0; i < 4; i++)
    #pragma unroll
    for (int j = 0; j < 4; j++) acc[i][j] = (f32x4){0.f,0.f,0.f,0.f};
  gemm128(Wot + (size_t)m0*512, aw + (size_t)b*S_LEN*512 + (size_t)n0*512, As, Bs, acc, tid);
  #pragma unroll
  for (int mi = 0; mi < 4; mi++)
    #pragma unroll
    for (int r = 0; r < 4; r++){
      int c = m0 + wr*64 + mi*16 + (lane >> 4)*4 + r;
      float bb = bo[c];
      size_t rowb = ((size_t)b*CIN + c)*S_LEN;
      #pragma unroll
      for (int nt = 0; nt < 4; nt++){
        int s = n0 + wc*64 + nt*16 + (lane & 15);
        out[rowb + s] = acc[mi][nt][r] + bb + x[rowb + s];
      }
    }
}

extern "C" void kernel_launch(void* const* d_in, const int* in_sizes, int n_in,
                              void* d_out, int out_size, void* d_ws, size_t ws_size,
                              hipStream_t stream){
  const float* x  = (const float*)d_in[0];
  const float* Wq = (const float*)d_in[1];
  const float* bq = (const float*)d_in[2];
  const float* Wk = (const float*)d_in[3];
  const float* bk = (const float*)d_in[4];
  const float* Wv = (const float*)d_in[5];
  const float* bv = (const float*)d_in[6];
  const float* Wo = (const float*)d_in[7];
  const float* bo = (const float*)d_in[8];
  float* out = (float*)d_out;

  unsigned short* p = (unsigned short*)d_ws;
  const size_t xs_e   = (size_t)NB*S_LEN*CIN;        // 4.19M
  const size_t qkv_e  = (size_t)NB*NH*S_LEN*DH;      // 4.19M
  unsigned short* xs    = p;                 p += xs_e;
  unsigned short* Wqkt  = p;                 p += 1024*512;
  unsigned short* Wvt   = p;                 p += 512*512;
  unsigned short* Wot   = p;                 p += 512*512;
  unsigned short* q_ws  = p;                 p += qkv_e;
  unsigned short* k_ws  = p;                 p += qkv_e;
  unsigned short* vt_ws = p;                 p += qkv_e;
  unsigned short* aw    = p;                 p += qkv_e;   // [b][s][512] bf16

  prep<<<1280, 256, 0, stream>>>(x, Wq, Wk, Wv, Wo, xs, Wqkt, Wvt, Wot);
  qkv128<<<dim3(8, 12, NB), 256, 0, stream>>>(xs, Wqkt, Wvt, bq, bk, bv, q_ws, k_ws, vt_ws);
  attn_fwd<<<512, 512, 0, stream>>>(q_ws, k_ws, vt_ws, aw);
  out128<<<dim3(4, 8, NB), 256, 0, stream>>>(Wot, aw, bo, x, out);
}

// Round 10
// 151.781 us; speedup vs baseline: 1.4234x; 1.0313x over previous
//
#include <hip/hip_runtime.h>

#define S_LEN 1024
#define CIN 512
#define NH 8
#define DH 64
#define NB 8

typedef short bf16x8 __attribute__((ext_vector_type(8)));
typedef float f32x4 __attribute__((ext_vector_type(4)));
typedef float f32x2 __attribute__((ext_vector_type(2)));

__device__ inline unsigned short f2bf(float f){
  union { float f; unsigned u; } v; v.f = f;
  unsigned r = v.u + 0x7FFFu + ((v.u >> 16) & 1u);
  return (unsigned short)(r >> 16);
}

// packed f32x2 -> bf16x2 (RNE, same numerics as f2bf), T12 recipe
__device__ inline unsigned cvt_pk_bf16(float a, float b){
  unsigned r;
  asm("v_cvt_pk_bf16_f32 %0, %1, %2" : "=v"(r) : "v"(a), "v"(b));
  return r;
}

// async global->LDS, 16B per lane. LDS dest = base + lane*16 (wave-uniform base).
__device__ inline void gload16(const void* g, void* l){
  __builtin_amdgcn_global_load_lds(
      (const __attribute__((address_space(1))) unsigned*)g,
      (__attribute__((address_space(3))) unsigned*)l, 16, 0, 0);
}

// swizzled frag read from LDS tile with 128B rows: phys col = kbyte ^ ((row&7)<<4)
__device__ inline bf16x8 ldfrag(const unsigned short* lds, int row, int kbyte){
  return *(const bf16x8*)((const char*)lds + row*128 + (kbyte ^ ((row & 7) << 4)));
}

// ---------------- prep: transpose+convert fp32 -> bf16 (64x64 tiles) ----------------
__global__ __launch_bounds__(256) void prep(const float* __restrict__ x,
    const float* __restrict__ Wq, const float* __restrict__ Wk,
    const float* __restrict__ Wv, const float* __restrict__ Wo,
    unsigned short* __restrict__ xs, unsigned short* __restrict__ Wqkt,
    unsigned short* __restrict__ Wvt, unsigned short* __restrict__ Wot){
  __shared__ unsigned short T[64*72];
  int bid = blockIdx.x, t = threadIdx.x;
  const float* src; unsigned short* dst; int ldS, r0, c0;
  if (bid < 1024){
    int b = bid >> 7, tt = bid & 127;
    src = x + (size_t)b*CIN*S_LEN; ldS = S_LEN;
    dst = xs + (size_t)b*S_LEN*CIN;
    r0 = (tt >> 4) * 64;            // c
    c0 = (tt & 15) * 64;            // s
  } else {
    int w = bid - 1024, mat = w >> 6, tt = w & 63;
    r0 = (tt >> 3) * 64; c0 = (tt & 7) * 64; ldS = 512;
    if (mat == 0){ src = Wq; dst = Wqkt; }
    else if (mat == 1){ src = Wk; dst = Wqkt + 512*512; }
    else if (mat == 2){ src = Wv; dst = Wvt; }
    else            { src = Wo; dst = Wot; }
  }
  int rl = t >> 4, cb = (t & 15) * 4;
  #pragma unroll
  for (int rr = 0; rr < 4; rr++){
    float4 f = *(const float4*)(src + (size_t)(r0 + rl + rr*16)*ldS + c0 + cb);
    int rc = rl + rr*16;
    T[(cb+0)*72 + rc] = f2bf(f.x);
    T[(cb+1)*72 + rc] = f2bf(f.y);
    T[(cb+2)*72 + rc] = f2bf(f.z);
    T[(cb+3)*72 + rc] = f2bf(f.w);
  }
  __syncthreads();
  int cl = t >> 2, rb = (t & 3) * 16;
  uint4 v0 = *(const uint4*)&T[cl*72 + rb];
  uint4 v1 = *(const uint4*)&T[cl*72 + rb + 8];
  *(uint4*)(dst + (size_t)(c0 + cl)*512 + r0 + rb) = v0;
  *(uint4*)(dst + (size_t)(c0 + cl)*512 + r0 + rb + 8) = v1;
}

// ---------------- 128x128 GEMM core: D = A * B^T (m97-style, proven) ----------------
__device__ inline void gemm128(const unsigned short* A, const unsigned short* B,
    unsigned short* As, unsigned short* Bs, f32x4 acc[4][4], int tid){
  int lane = tid & 63, w = tid >> 6;
  int wr = w >> 1, wc = w & 1;
  int srow = lane >> 3;
  int scol8 = ((lane & 7) ^ (lane >> 3)) << 3;   // pre-swizzled element offset in row
  for (int k0 = 0; k0 < 512; k0 += 64){
    __syncthreads();
    #pragma unroll
    for (int i = 0; i < 4; i++){
      int r0 = w*32 + i*8;
      gload16(A + (size_t)(r0 + srow)*512 + k0 + scol8, As + r0*64);
      gload16(B + (size_t)(r0 + srow)*512 + k0 + scol8, Bs + r0*64);
    }
    __syncthreads();
    #pragma unroll
    for (int kt = 0; kt < 2; kt++){
      bf16x8 af[4], bfv[4];
      #pragma unroll
      for (int i = 0; i < 4; i++){
        af[i]  = ldfrag(As, wr*64 + i*16 + (lane & 15), kt*64 + ((lane >> 4) << 4));
        bfv[i] = ldfrag(Bs, wc*64 + i*16 + (lane & 15), kt*64 + ((lane >> 4) << 4));
      }
      #pragma unroll
      for (int mi = 0; mi < 4; mi++)
        #pragma unroll
        for (int ni = 0; ni < 4; ni++)
          acc[mi][ni] = __builtin_amdgcn_mfma_f32_16x16x32_bf16(af[mi], bfv[ni], acc[mi][ni], 0,0,0);
    }
  }
}

// ---------------- merged QKV projection (unchanged) ----------------
__global__ __launch_bounds__(256) void qkv128(const unsigned short* __restrict__ xs,
    const unsigned short* __restrict__ Wqkt, const unsigned short* __restrict__ Wvt,
    const float* __restrict__ bq, const float* __restrict__ bk,
    const float* __restrict__ bv, unsigned short* __restrict__ q_ws,
    unsigned short* __restrict__ k_ws, unsigned short* __restrict__ vt_ws){
  __shared__ __align__(16) unsigned short As[8192], Bs[8192];
  int tid = threadIdx.x, lane = tid & 63, w = tid >> 6, wr = w >> 1, wc = w & 1;
  int bx = blockIdx.x, by = blockIdx.y, b = blockIdx.z;
  f32x4 acc[4][4];
  #pragma unroll
  for (int i = 0; i < 4; i++)
    #pragma unroll
    for (int j = 0; j < 4; j++) acc[i][j] = (f32x4){0.f,0.f,0.f,0.f};
  if (by < 8){
    int m0 = bx * 128, n0 = by * 128;
    gemm128(xs + (size_t)b*S_LEN*CIN + (size_t)m0*512, Wqkt + (size_t)n0*512, As, Bs, acc, tid);
    int jb = (n0 + wc*64) >> 6;          // 0..15
    int isK = jb >= 8, h = jb & 7;
    const float* bias = isK ? bk : bq;
    unsigned short* dst = (isK ? k_ws : q_ws) + ((size_t)(b*NH + h))*S_LEN*DH;
    #pragma unroll
    for (int nt = 0; nt < 4; nt++){
      int d = nt*16 + (lane & 15);
      float bb = bias[(jb & 7)*64 + d];
      #pragma unroll
      for (int mi = 0; mi < 4; mi++)
        #pragma unroll
        for (int r = 0; r < 4; r++){
          int s = m0 + wr*64 + mi*16 + (lane >> 4)*4 + r;
          dst[(size_t)s*DH + d] = f2bf(acc[mi][nt][r] + bb);
        }
    }
  } else {
    int m0 = (by - 8) * 128, n0 = bx * 128;
    gemm128(Wvt + (size_t)m0*512, xs + (size_t)b*S_LEN*CIN + (size_t)n0*512, As, Bs, acc, tid);
    #pragma unroll
    for (int mi = 0; mi < 4; mi++)
      #pragma unroll
      for (int r = 0; r < 4; r++){
        int j = m0 + wr*64 + mi*16 + (lane >> 4)*4 + r;
        int h = j >> 6, dv = j & 63;
        float bb = bv[j];
        unsigned short* dst = vt_ws + ((size_t)(b*NH + h)*DH + dv)*S_LEN;
        #pragma unroll
        for (int nt = 0; nt < 4; nt++){
          int s = n0 + wc*64 + nt*16 + (lane & 15);
          dst[s] = f2bf(acc[mi][nt][r] + bb);
        }
      }
  }
}

// ---------------- flash attention: 8 waves / 128 q-rows, dbuf K/V, defer-max,
// setprio around MFMA clusters. Fragment math identical to the proven core.
__global__ __launch_bounds__(512) void attn_fwd(const unsigned short* __restrict__ qw,
    const unsigned short* __restrict__ kw, const unsigned short* __restrict__ vtw,
    unsigned short* __restrict__ aw){
  __shared__ __align__(16) unsigned short Ks[2][4096], Vs[2][4096], Ps[8192];
  int tid = threadIdx.x, lane = tid & 63, wid = tid >> 6;   // wid 0..7
  int bid = blockIdx.x;                 // 512 blocks
  int idx = bid >> 3;                   // 0..63
  int qb = idx & 7;                     // q block (128 rows)
  int bh = (bid & 7)*8 + (idx >> 3);    // bh pinned to XCD
  int qrw = lane & 15, g = lane >> 4;
  int q0 = qb*128 + wid*16;
  const unsigned short* qrow = qw + ((size_t)bh*S_LEN + q0 + qrw)*DH;
  bf16x8 qf0 = *(const bf16x8*)(qrow + g*8);
  bf16x8 qf1 = *(const bf16x8*)(qrow + 32 + g*8);
  unsigned short* myP = Ps + wid*1024;
  f32x4 oacc[4];
  #pragma unroll
  for (int i = 0; i < 4; i++) oacc[i] = (f32x4){0.f,0.f,0.f,0.f};
  float mrun = -3e38f, lrun = 0.f;
  int srow = lane >> 3, scol8 = ((lane & 7) ^ (lane >> 3)) << 3;
  const unsigned short* kbase = kw + (size_t)bh*S_LEN*DH;
  const unsigned short* vbase = vtw + (size_t)bh*DH*S_LEN;
  const float SC = 0.125f * 1.44269504f;   // scale * log2(e)
  int r0 = wid*8;                          // this wave's 8 staging rows
  gload16(kbase + (size_t)(r0 + srow)*DH + scol8, Ks[0] + r0*64);
  gload16(vbase + (size_t)(r0 + srow)*S_LEN + scol8, Vs[0] + r0*64);
  __syncthreads();
  int cur = 0;

  for (int kv0 = 0; kv0 < S_LEN; kv0 += 64){
    if (kv0 + 64 < S_LEN){
      gload16(kbase + (size_t)(kv0 + 64 + r0 + srow)*DH + scol8, Ks[cur^1] + r0*64);
      gload16(vbase + (size_t)(r0 + srow)*S_LEN + kv0 + 64 + scol8, Vs[cur^1] + r0*64);
    }
    const unsigned short* Kc = Ks[cur];
    const unsigned short* Vc = Vs[cur];

    // S^T tile: D'[kcol][q] via mfma(K, Q)
    f32x4 st[4];
    __builtin_amdgcn_s_setprio(1);
    #pragma unroll
    for (int mt = 0; mt < 4; mt++){
      f32x4 a = (f32x4){0.f,0.f,0.f,0.f};
      a = __builtin_amdgcn_mfma_f32_16x16x32_bf16(
            ldfrag(Kc, mt*16 + qrw, g << 4), qf0, a, 0,0,0);
      a = __builtin_amdgcn_mfma_f32_16x16x32_bf16(
            ldfrag(Kc, mt*16 + qrw, 64 + (g << 4)), qf1, a, 0,0,0);
      st[mt] = a;
    }
    __builtin_amdgcn_s_setprio(0);
    float vmax = -3e38f;
    #pragma unroll
    for (int mt = 0; mt < 4; mt++)
      #pragma unroll
      for (int r = 0; r < 4; r++){
        st[mt][r] *= SC;
        vmax = fmaxf(vmax, st[mt][r]);
      }
    vmax = fmaxf(vmax, __shfl_xor(vmax, 16));
    vmax = fmaxf(vmax, __shfl_xor(vmax, 32));
    // T13 defer-max: only rescale when some row's max grew by > 8 (log2 units).
    if (!__all(vmax <= mrun + 8.f)){
      float mnew = fmaxf(mrun, vmax);
      float corr = __builtin_amdgcn_exp2f(mrun - mnew);
      lrun *= corr;
      #pragma unroll
      for (int mt = 0; mt < 4; mt++) oacc[mt] *= corr;   // col q = qrw: per-lane
      mrun = mnew;
    }
    float psum = 0.f;
    #pragma unroll
    for (int mt = 0; mt < 4; mt++){
      float p0 = __builtin_amdgcn_exp2f(st[mt][0] - mrun);
      float p1 = __builtin_amdgcn_exp2f(st[mt][1] - mrun);
      float p2 = __builtin_amdgcn_exp2f(st[mt][2] - mrun);
      float p3 = __builtin_amdgcn_exp2f(st[mt][3] - mrun);
      psum += (p0 + p1) + (p2 + p3);
      uint2 pw; pw.x = cvt_pk_bf16(p0, p1); pw.y = cvt_pk_bf16(p2, p3);
      *(uint2*)((char*)myP + qrw*128 + ((mt*32 + g*8) ^ ((qrw & 7) << 4))) = pw;
    }
    psum += __shfl_xor(psum, 16);
    psum += __shfl_xor(psum, 32);
    lrun += psum;
    // O^T += V^T P^T : mfma(A=VT[dv][k], B=P[q][k]) -> D[dv][q]
    __builtin_amdgcn_s_setprio(1);
    #pragma unroll
    for (int kt = 0; kt < 2; kt++){
      bf16x8 pf = *(const bf16x8*)((char*)myP + qrw*128 +
                    ((kt*64 + (g << 4)) ^ ((qrw & 7) << 4)));
      #pragma unroll
      for (int mt = 0; mt < 4; mt++)
        oacc[mt] = __builtin_amdgcn_mfma_f32_16x16x32_bf16(
            ldfrag(Vc, mt*16 + qrw, kt*64 + (g << 4)), pf, oacc[mt], 0,0,0);
    }
    __builtin_amdgcn_s_setprio(0);
    __syncthreads();   // next tile staged + everyone done with cur
    cur ^= 1;
  }
  float inv = 1.f / lrun;   // per q-row = qrw
  #pragma unroll
  for (int mt = 0; mt < 4; mt++){
    uint2 pw;
    pw.x = cvt_pk_bf16(oacc[mt][0] * inv, oacc[mt][1] * inv);
    pw.y = cvt_pk_bf16(oacc[mt][2] * inv, oacc[mt][3] * inv);
    *(uint2*)((char*)myP + qrw*128 + ((mt*32 + g*8) ^ ((qrw & 7) << 4))) = pw;
  }
  int b = bh >> 3, h = bh & 7;
  int rr = lane >> 2, cc = lane & 3;   // row q_local, 16-elem chunk
  uint4 lo = *(const uint4*)((char*)myP + rr*128 + ((cc*32) ^ ((rr & 7) << 4)));
  uint4 hi = *(const uint4*)((char*)myP + rr*128 + (((cc*32) + 16) ^ ((rr & 7) << 4)));
  unsigned short* obase = aw + ((size_t)b*S_LEN + (q0 + rr))*512 + h*64 + cc*16;
  *(uint4*)obase = lo;
  *(uint4*)(obase + 8) = hi;
}

// ---------------- out projection: 128c x 64s tiles (512 blocks -> 2/CU) ----------------
__global__ __launch_bounds__(256) void out64(const unsigned short* __restrict__ Wot,
    const unsigned short* __restrict__ aw, const float* __restrict__ bo,
    const float* __restrict__ x, float* __restrict__ out){
  __shared__ __align__(16) unsigned short As[8192], Bs[4096];
  int tid = threadIdx.x, lane = tid & 63, w = tid >> 6, wr = w >> 1, wc = w & 1;
  int m0 = blockIdx.x * 128, n0 = blockIdx.y * 64, b = blockIdx.z;
  const unsigned short* A = Wot + (size_t)m0*512;
  const unsigned short* B = aw + (size_t)b*S_LEN*512 + (size_t)n0*512;
  int srow = lane >> 3;
  int scol8 = ((lane & 7) ^ (lane >> 3)) << 3;
  f32x4 acc[4][2];
  #pragma unroll
  for (int i = 0; i < 4; i++)
    #pragma unroll
    for (int j = 0; j < 2; j++) acc[i][j] = (f32x4){0.f,0.f,0.f,0.f};
  for (int k0 = 0; k0 < 512; k0 += 64){
    __syncthreads();
    #pragma unroll
    for (int i = 0; i < 4; i++){
      int r0 = w*32 + i*8;
      gload16(A + (size_t)(r0 + srow)*512 + k0 + scol8, As + r0*64);
    }
    #pragma unroll
    for (int i = 0; i < 2; i++){
      int r0 = w*16 + i*8;
      gload16(B + (size_t)(r0 + srow)*512 + k0 + scol8, Bs + r0*64);
    }
    __syncthreads();
    #pragma unroll
    for (int kt = 0; kt < 2; kt++){
      bf16x8 af[4], bfv[2];
      #pragma unroll
      for (int i = 0; i < 4; i++)
        af[i] = ldfrag(As, wr*64 + i*16 + (lane & 15), kt*64 + ((lane >> 4) << 4));
      #pragma unroll
      for (int i = 0; i < 2; i++)
        bfv[i] = ldfrag(Bs, wc*32 + i*16 + (lane & 15), kt*64 + ((lane >> 4) << 4));
      #pragma unroll
      for (int mi = 0; mi < 4; mi++)
        #pragma unroll
        for (int ni = 0; ni < 2; ni++)
          acc[mi][ni] = __builtin_amdgcn_mfma_f32_16x16x32_bf16(af[mi], bfv[ni], acc[mi][ni], 0,0,0);
    }
  }
  #pragma unroll
  for (int mi = 0; mi < 4; mi++)
    #pragma unroll
    for (int r = 0; r < 4; r++){
      int c = m0 + wr*64 + mi*16 + (lane >> 4)*4 + r;
      float bb = bo[c];
      size_t rowb = ((size_t)b*CIN + c)*S_LEN;
      #pragma unroll
      for (int nt = 0; nt < 2; nt++){
        int s = n0 + wc*32 + nt*16 + (lane & 15);
        out[rowb + s] = acc[mi][nt][r] + bb + x[rowb + s];
      }
    }
}

extern "C" void kernel_launch(void* const* d_in, const int* in_sizes, int n_in,
                              void* d_out, int out_size, void* d_ws, size_t ws_size,
                              hipStream_t stream){
  const float* x  = (const float*)d_in[0];
  const float* Wq = (const float*)d_in[1];
  const float* bq = (const float*)d_in[2];
  const float* Wk = (const float*)d_in[3];
  const float* bk = (const float*)d_in[4];
  const float* Wv = (const float*)d_in[5];
  const float* bv = (const float*)d_in[6];
  const float* Wo = (const float*)d_in[7];
  const float* bo = (const float*)d_in[8];
  float* out = (float*)d_out;

  unsigned short* p = (unsigned short*)d_ws;
  const size_t xs_e   = (size_t)NB*S_LEN*CIN;        // 4.19M
  const size_t qkv_e  = (size_t)NB*NH*S_LEN*DH;      // 4.19M
  unsigned short* xs    = p;                 p += xs_e;
  unsigned short* Wqkt  = p;                 p += 1024*512;
  unsigned short* Wvt   = p;                 p += 512*512;
  unsigned short* Wot   = p;                 p += 512*512;
  unsigned short* q_ws  = p;                 p += qkv_e;
  unsigned short* k_ws  = p;                 p += qkv_e;
  unsigned short* vt_ws = p;                 p += qkv_e;
  unsigned short* aw    = p;                 p += qkv_e;   // [b][s][512] bf16

  prep<<<1280, 256, 0, stream>>>(x, Wq, Wk, Wv, Wo, xs, Wqkt, Wvt, Wot);
  qkv128<<<dim3(8, 12, NB), 256, 0, stream>>>(xs, Wqkt, Wvt, bq, bk, bv, q_ws, k_ws, vt_ws);
  attn_fwd<<<512, 512, 0, stream>>>(q_ws, k_ws, vt_ws, aw);
  out64<<<dim3(4, 16, NB), 256, 0, stream>>>(Wot, aw, bo, x, out);
}